// Round 15
// baseline (69.876 us; speedup 1.0000x reference)
//
#include <hip/hip_runtime.h>
#include <math.h>

// LatentSDE (L=C=D=1, H=64), all nets tabulated, thread-per-b recurrence.
// R14 analysis: at 32 blk x 256 thr, 4 waves/CU share one LDS pipe; each
// wave-step = 4 random-gather ds_read_b128 (~40+cy each w/ conflicts) ->
// ~600-800cy serialized pipe time per CU-step ~ matches measured 1000cy.
// R15 experiment: 64 blk x 128 thr (2 waves/CU over 64 CUs) halves LDS-pipe
// sharing. Numerics/layout identical to R14 (absmax 0.0): tier1 z[-128,128]
// dz=1/4, tier2 z[-8192,8192] dz=16, 48B entries, cubic-Lagrange c-nodes
// {-3,-1,1,3}, 4-deep register prefetch, exact-MLP fallback (rare).

#define B_SZ 8192
#define T_SZ 128
#define NBLK 64                  // scan blocks (128 thr each)
#define BTHR 128

#define NT1 1025                 // tier1 entries (z in [-128,128], dz=1/4)
#define NT2 1025                 // tier2 entries (z in [-8192,8192], dz=16)
#define NEE 1024                 // encoder pairs (x in [-8,8], dx=1/64)
#define NENT (NT1 + NT2 + NEE)   // 3074 build entries (one wave each)

#define ENT_F4 3                       // 48B entry stride (8 bank-quads)
#define MT_FLOATS (4 * ENT_F4 * (NT1 + NT2))  // 24600 floats = 98.4KB
#define T2_BASE4 (ENT_F4 * NT1)        // 3075
#define ET2G_OFF  MT_FLOATS            // et2 (global only), 2048 floats
#define TABG_FLOATS (MT_FLOATS + 2048) // 26648

#define NXI 1024
#define XSF 64.0f
#define XOF 512.0f

#if __has_builtin(__builtin_amdgcn_rcpf)
#define RCPF(x) __builtin_amdgcn_rcpf(x)
#else
#define RCPF(x) (1.0f / (x))
#endif
#if __has_builtin(__builtin_amdgcn_sqrtf)
#define SQRTF(x) __builtin_amdgcn_sqrtf(x)
#else
#define SQRTF(x) sqrtf(x)
#endif

__device__ __forceinline__ float sp_precise(float a) {
  return fmaxf(a, 0.0f) + log1pf(expf(-fabsf(a)));
}
__device__ __forceinline__ float wsum64(float v) {
  #pragma unroll
  for (int m = 1; m <= 32; m <<= 1) v += __shfl_xor(v, m);
  return v;
}

// ---------------- build: one wave per entry (R11-verified) ----------------
__global__ __launch_bounds__(256) void build_tabs(
    const float* __restrict__ ew1, const float* __restrict__ eb1,
    const float* __restrict__ ew2, const float* __restrict__ eb2,
    const float* __restrict__ fw1, const float* __restrict__ fb1,
    const float* __restrict__ fw2, const float* __restrict__ fb2,
    const float* __restrict__ hw1, const float* __restrict__ hb1,
    const float* __restrict__ hw2, const float* __restrict__ hb2,
    const float* __restrict__ gw1, const float* __restrict__ gb1,
    const float* __restrict__ gw2, const float* __restrict__ gb2,
    const float* __restrict__ pw1, const float* __restrict__ pb1,
    const float* __restrict__ pw2, const float* __restrict__ pb2,
    float* __restrict__ tabs, int* __restrict__ ctr)
{
  const int gtid = blockIdx.x * 256 + threadIdx.x;
  if (gtid == 0) *ctr = 0;
  const int ent  = gtid >> 6;
  const int lane = threadIdx.x & 63;
  if (ent >= NENT) return;

  if (ent < NT1 + NT2) {
    const bool t1 = ent < NT1;
    const int  i  = t1 ? ent : (ent - NT1);
    const float z = t1 ? (-128.0f + (float)i * 0.25f)
                       : (-8192.0f + (float)i * 16.0f);
    const int base4 = (t1 ? 0 : T2_BASE4) + ENT_F4 * i;

    const float az = fmaf(z, fw1[lane], fb1[lane]);
    const float wc = fw1[64 + lane], w2 = fw2[lane];
    float s0 = sp_precise(fmaf(-3.0f, wc, az)) * w2;
    float s1 = sp_precise(fmaf(-1.0f, wc, az)) * w2;
    float s2 = sp_precise(fmaf( 1.0f, wc, az)) * w2;
    float s3 = sp_precise(fmaf( 3.0f, wc, az)) * w2;
    float sh = sp_precise(fmaf(z, hw1[lane], hb1[lane])) * hw2[lane];
    float sg = sp_precise(fmaf(z, gw1[lane], gb1[lane])) * gw2[lane];
    float sp = sp_precise(fmaf(z, pw1[lane], pb1[lane])) * pw2[lane];
    s0 = wsum64(s0); s1 = wsum64(s1); s2 = wsum64(s2); s3 = wsum64(s3);
    sh = wsum64(sh); sg = wsum64(sg); sp = wsum64(sp);
    if (lane == 0) {
      const float fb = fb2[0];
      ((float4*)tabs)[base4]     = make_float4(s0 + fb, s1 + fb, s2 + fb, s3 + fb);
      ((float4*)tabs)[base4 + 1] = make_float4(
          sh + hb2[0],
          1.0f / (1.0f + expf(-(sg + gb2[0]))),
          sp + pb2[0], 0.0f);
      ((float4*)tabs)[base4 + 2] = make_float4(0.f, 0.f, 0.f, 0.f);  // pad
    }
  } else {
    const int i = ent - (NT1 + NT2);
    const float x0 = -8.0f + (float)i * (1.0f / 64.0f);
    const float x1 = x0 + (1.0f / 64.0f);
    const float w = ew1[lane], bb = eb1[lane], w2 = ew2[lane];
    float s0 = sp_precise(fmaf(x0, w, bb)) * w2;
    float s1 = sp_precise(fmaf(x1, w, bb)) * w2;
    s0 = wsum64(s0); s1 = wsum64(s1);
    if (lane == 0) {
      const float eb = eb2[0];
      ((float2*)(tabs + ET2G_OFF))[i] = make_float2(s0 + eb, s1 + eb);
    }
  }
}

// ---------------- pre-pass: ctx[t,b] = enc(xs[t,b]) ----------------
__global__ __launch_bounds__(256) void ctx_pre(
    const float* __restrict__ xs, const float* __restrict__ tabs,
    float* __restrict__ ctx)
{
  const int i = blockIdx.x * 256 + threadIdx.x;
  const float2* et2 = (const float2*)(tabs + ET2G_OFF);
  const float s = fmaf(xs[i], XSF, XOF);
  const float sc = fminf(fmaxf(s, 0.0f), (float)(NXI - 1));
  const int ii = (int)sc;
  const float fr = s - (float)ii;
  const float2 e = et2[ii];
  ctx[i] = fmaf(fr, e.y - e.x, e.x);
}

// ---------------- scan: 64 blocks x 128 thr (2 waves/CU, 64 CUs) ----------------
__global__ __launch_bounds__(BTHR) void sde_scan(
    const float* __restrict__ xs, const float* __restrict__ ts,
    const float* __restrict__ noise_std, const float* __restrict__ eps0,
    const float* __restrict__ dW, const float* __restrict__ ctx,
    const float* __restrict__ qw,  const float* __restrict__ qb,
    const float* __restrict__ fw1, const float* __restrict__ fb1,
    const float* __restrict__ fw2, const float* __restrict__ fb2,
    const float* __restrict__ hw1, const float* __restrict__ hb1,
    const float* __restrict__ hw2, const float* __restrict__ hb2,
    const float* __restrict__ gw1, const float* __restrict__ gb1,
    const float* __restrict__ gw2, const float* __restrict__ gb2,
    const float* __restrict__ pw1, const float* __restrict__ pb1,
    const float* __restrict__ pw2, const float* __restrict__ pb2,
    const float* __restrict__ pz0_mean, const float* __restrict__ pz0_logstd,
    const float* __restrict__ tabsrc,
    int* __restrict__ ctr, float* __restrict__ partA, float* __restrict__ partB,
    float* __restrict__ out)
{
  __shared__ __align__(16) float tab[MT_FLOATS];
  __shared__ float la[BTHR], lb[BTHR];
  __shared__ int lastflag;

  const int tid = threadIdx.x;
  const int b   = blockIdx.x * BTHR + tid;

  { // stage z-table
    const float4* s4 = (const float4*)tabsrc;
    float4* d4 = (float4*)tab;
    for (int i = tid; i < MT_FLOATS / 4; i += BTHR) d4[i] = s4[i];
  }
  __syncthreads();

  const float4* tab4 = (const float4*)tab;

  const float fb2s = fb2[0], hb2s = hb2[0], gb2s = gb2[0], pb2s = pb2[0];
  const float qw0 = qw[0], qw1 = qw[1], qb0 = qb[0], qb1 = qb[1];
  const float ns = noise_std[0];
  const float inv_ns = 1.0f / ns;
  const float nh_i2 = -0.5f * inv_ns * inv_ns;
  const float pm = pz0_mean[0], pls = pz0_logstd[0];

  auto lagr = [&](float c) {    // cubic Lagrange, nodes {-3,-1,1,3}
    const float c2 = c * c;
    const float p1 = c2 - 1.0f, p3 = c2 - 9.0f;
    return make_float4(p1 * (c - 3.0f) * (-1.0f / 48.0f),
                       p3 * (c - 1.0f) * ( 1.0f / 16.0f),
                       p3 * (c + 1.0f) * (-1.0f / 16.0f),
                       p1 * (c + 3.0f) * ( 1.0f / 48.0f));
  };
  auto hgp_exact = [&](float z_, float& hv_, float& gv_, float& pv_) {
    float sh = 0.f, sg = 0.f, sp = 0.f;
    for (int j = 0; j < 64; ++j) {
      sh = fmaf(sp_precise(fmaf(z_, hw1[j], hb1[j])), hw2[j], sh);
      sg = fmaf(sp_precise(fmaf(z_, gw1[j], gb1[j])), gw2[j], sg);
      sp = fmaf(sp_precise(fmaf(z_, pw1[j], pb1[j])), pw2[j], sp);
    }
    hv_ = sh + hb2s;
    gv_ = 1.0f / (1.0f + expf(-(sg + gb2s)));
    pv_ = sp + pb2s;
  };
  auto f_exact = [&](float z_, float c_) {
    float s = 0.f;
    for (int j = 0; j < 64; ++j)
      s = fmaf(sp_precise(fmaf(z_, fw1[j], fmaf(c_, fw1[64 + j], fb1[j]))), fw2[j], s);
    return s + fb2s;
  };
  auto zidx = [&](float z_, int& base4_, float& frac_, bool& inr_) {
    const float s1 = fmaf(z_, 4.0f, 512.0f);        // tier1 (dz=1/4)
    const float s2 = fmaf(z_, 0.0625f, 512.0f);     // tier2 (dz=16)
    const bool t1 = (s1 >= 0.0f) && (s1 <= 1024.0f);
    const bool t2 = (s2 >= 0.0f) && (s2 <= 1024.0f);
    inr_ = t1 || t2;
    const float sf = t1 ? s1 : fminf(fmaxf(s2, 0.0f), 1024.0f);
    const int fi = min((int)sf, 1023);
    base4_ = (t1 ? 0 : T2_BASE4) + ENT_F4 * fi;
    frac_ = sf - (float)fi;
  };

  // ---- prologue ----
  const float x0 = xs[b];
  const float c0v = ctx[b];
  const float qm  = fmaf(c0v, qw0, qb0);
  const float qls = fmaf(c0v, qw1, qb1);
  float z = fmaf(__expf(qls), eps0[b], qm);
  const float dqm = qm - pm;
  const float kl = (pls - qls)
                 + (__expf(2.0f * qls) + dqm * dqm) * (0.5f * __expf(-2.0f * pls))
                 - 0.5f;

  // 4-deep prefetch: slot j holds {xs[(k+1)B+b], ctx[(k+1)B+b], dW[kB+b]}
  float xbuf0 = xs[1 * B_SZ + b], cbuf0 = ctx[1 * B_SZ + b], wbuf0 = dW[0 * B_SZ + b];
  float xbuf1 = xs[2 * B_SZ + b], cbuf1 = ctx[2 * B_SZ + b], wbuf1 = dW[1 * B_SZ + b];
  float xbuf2 = xs[3 * B_SZ + b], cbuf2 = ctx[3 * B_SZ + b], wbuf2 = dW[2 * B_SZ + b];
  float xbuf3 = xs[4 * B_SZ + b], cbuf3 = ctx[4 * B_SZ + b], wbuf3 = dW[3 * B_SZ + b];

  bool zin; int zb4; float zfr;
  float4 q0a, q0b, q1a, q1b;
  float hv, gv, pv;
  zidx(z, zb4, zfr, zin);
  q0a = tab4[zb4]; q0b = tab4[zb4 + 1];
  q1a = tab4[zb4 + ENT_F4]; q1b = tab4[zb4 + ENT_F4 + 1];
  if (zin) {
    hv = fmaf(zfr, q1b.x - q0b.x, q0b.x);
    gv = fmaf(zfr, q1b.y - q0b.y, q0b.y);
    pv = fmaf(zfr, q1b.z - q0b.z, q0b.z);
  } else {
    hgp_exact(z, hv, gv, pv);
  }
  float lp_sum; { const float d = x0 - pv; lp_sum = nh_i2 * d * d; }
  float lr_sum = 0.0f;

#define STEP(K, J) { \
    const float dt = ts[(K) + 1] - ts[(K)]; \
    const float sq = SQRTF(dt); \
    const float cc = cbuf##J; \
    const float4 L = lagr(cc); \
    const bool cin = fabsf(cc) <= 3.0f; \
    float fv; \
    if (zin && cin) { \
      const float n0 = fmaf(zfr, q1a.x - q0a.x, q0a.x); \
      const float n1 = fmaf(zfr, q1a.y - q0a.y, q0a.y); \
      const float n2 = fmaf(zfr, q1a.z - q0a.z, q0a.z); \
      const float n3 = fmaf(zfr, q1a.w - q0a.w, q0a.w); \
      fv = n0 * L.x + n1 * L.y + n2 * L.z + n3 * L.w; \
    } else { \
      fv = f_exact(z, cc); \
    } \
    const float gvs = fmaxf(gv, 1e-6f); \
    const float uu = (fv - hv) * RCPF(gvs); \
    lr_sum = fmaf((0.5f * dt) * uu, uu, lr_sum); \
    z = fmaf(gvs * wbuf##J, sq, fmaf(fv, dt, z)); \
    zidx(z, zb4, zfr, zin); \
    q0a = tab4[zb4]; q0b = tab4[zb4 + 1]; \
    q1a = tab4[zb4 + ENT_F4]; q1b = tab4[zb4 + ENT_F4 + 1]; \
    /* refill slot J for step K+4 (3+ steps of latency slack) */ \
    const int kk_ = (K) + 4; \
    const int ix_ = ((kk_ + 1 < T_SZ) ? kk_ + 1 : T_SZ - 1) * B_SZ + b; \
    const float xb_n = xs[ix_]; \
    const float cb_n = ctx[ix_]; \
    const float wb_n = (kk_ < T_SZ - 1) ? dW[kk_ * B_SZ + b] : 0.0f; \
    if (zin) { \
      hv = fmaf(zfr, q1b.x - q0b.x, q0b.x); \
      gv = fmaf(zfr, q1b.y - q0b.y, q0b.y); \
      pv = fmaf(zfr, q1b.z - q0b.z, q0b.z); \
    } else { \
      hgp_exact(z, hv, gv, pv); \
    } \
    const float d_ = xbuf##J - pv; \
    lp_sum = fmaf(nh_i2 * d_, d_, lp_sum); \
    xbuf##J = xb_n; cbuf##J = cb_n; wbuf##J = wb_n; \
  }

  // ---- Euler-Maruyama scan: 127 steps = 31*4 + 3 ----
  for (int k = 0; k < 124; k += 4) {
    STEP(k, 0); STEP(k + 1, 1); STEP(k + 2, 2); STEP(k + 3, 3);
  }
  STEP(124, 0); STEP(125, 1); STEP(126, 2);
#undef STEP

  // ---- fused deterministic reduction ----
  la[tid] = lp_sum; lb[tid] = kl + lr_sum;
  __syncthreads();
  for (int s = BTHR / 2; s > 0; s >>= 1) {
    if (tid < s) { la[tid] += la[tid + s]; lb[tid] += lb[tid + s]; }
    __syncthreads();
  }
  if (tid == 0) {
    partA[blockIdx.x] = la[0]; partB[blockIdx.x] = lb[0];
    __threadfence();
    lastflag = (atomicAdd(ctr, 1) == NBLK - 1) ? 1 : 0;
  }
  __syncthreads();
  if (lastflag) {
    __threadfence();
    la[tid] = (tid < NBLK) ? partA[tid] : 0.0f;
    lb[tid] = (tid < NBLK) ? partB[tid] : 0.0f;
    __syncthreads();
    for (int s = BTHR / 2; s > 0; s >>= 1) {
      if (tid < s) { la[tid] += la[tid + s]; lb[tid] += lb[tid + s]; }
      __syncthreads();
    }
    if (tid == 0) {
      out[0] = la[0] / (float)B_SZ
             + (float)T_SZ * (-__logf(ns) - 0.9189385332046727f);
      out[1] = lb[0] / (float)B_SZ;
    }
  }
}

extern "C" void kernel_launch(void* const* d_in, const int* in_sizes, int n_in,
                              void* d_out, int out_size, void* d_ws, size_t ws_size,
                              hipStream_t stream) {
  const float* xs        = (const float*)d_in[0];
  const float* ts        = (const float*)d_in[1];
  const float* noise_std = (const float*)d_in[2];
  const float* eps0      = (const float*)d_in[3];
  const float* dW        = (const float*)d_in[4];
  const float* ew1 = (const float*)d_in[5];
  const float* eb1 = (const float*)d_in[6];
  const float* ew2 = (const float*)d_in[7];
  const float* eb2 = (const float*)d_in[8];
  const float* qw  = (const float*)d_in[9];
  const float* qb  = (const float*)d_in[10];
  const float* fw1 = (const float*)d_in[11];
  const float* fb1 = (const float*)d_in[12];
  const float* fw2 = (const float*)d_in[13];
  const float* fb2 = (const float*)d_in[14];
  const float* hw1 = (const float*)d_in[15];
  const float* hb1 = (const float*)d_in[16];
  const float* hw2 = (const float*)d_in[17];
  const float* hb2 = (const float*)d_in[18];
  const float* gw1 = (const float*)d_in[19];
  const float* gb1 = (const float*)d_in[20];
  const float* gw2 = (const float*)d_in[21];
  const float* gb2 = (const float*)d_in[22];
  const float* pw1 = (const float*)d_in[23];
  const float* pb1 = (const float*)d_in[24];
  const float* pw2 = (const float*)d_in[25];
  const float* pb2 = (const float*)d_in[26];
  const float* pz0_mean   = (const float*)d_in[27];
  const float* pz0_logstd = (const float*)d_in[28];
  float* out = (float*)d_out;

  float* tabs  = (float*)d_ws;                       // [TABG_FLOATS]
  int*   ctr   = (int*)(tabs + TABG_FLOATS);         // [1] (+pad)
  float* partA = tabs + TABG_FLOATS + 4;             // [NBLK]
  float* partB = partA + NBLK;                       // [NBLK]
  float* ctxb  = tabs + TABG_FLOATS + 144;           // [T*B]

  build_tabs<<<(NENT * 64 + 255) / 256, 256, 0, stream>>>(
      ew1, eb1, ew2, eb2, fw1, fb1, fw2, fb2,
      hw1, hb1, hw2, hb2, gw1, gb1, gw2, gb2,
      pw1, pb1, pw2, pb2, tabs, ctr);

  ctx_pre<<<(T_SZ * B_SZ) / 256, 256, 0, stream>>>(xs, tabs, ctxb);

  sde_scan<<<NBLK, BTHR, 0, stream>>>(
      xs, ts, noise_std, eps0, dW, ctxb, qw, qb,
      fw1, fb1, fw2, fb2, hw1, hb1, hw2, hb2,
      gw1, gb1, gw2, gb2, pw1, pb1, pw2, pb2,
      pz0_mean, pz0_logstd, tabs, ctr, partA, partB, out);
}

// Round 16
// 66.458 us; speedup vs baseline: 1.0514x; 1.0514x over previous
//
#include <hip/hip_runtime.h>
#include <math.h>

// LatentSDE (L=C=D=1, H=64), all nets tabulated. R14/R15 falsified LDS-pipe
// sharing: wall is the PER-WAVE chain (~1090cy/step), dominated by 4x 64-lane
// random-gather ds_read_b128 with only 128 waves to hide them.
// R16: 8-lane groups, 8 b/wave -> ONE ds_read_b64 gather serves a whole
// group-step (entry = 10 floats {f-3,f-1,f1,f3,h,g,p,pads}; lanes read
// float2 slices of entries zi,zi+1). Cross-lane: 1 ds_swizzle xor4 +
// 4 DPP quad_perms (R3-verified). 1024 waves = 4/CU over 256 CUs.
// Numerics unchanged (absmax 0.0 since R10): tier1 z[-128,128] dz=1/4,
// tier2 z[-8192,8192] dz=16, cubic-Lagrange c-nodes {-3,-1,1,3},
// exact-MLP fallback (rare, exec-masked, shuffle-free).

#define B_SZ 8192
#define T_SZ 128
#define NBLK 256                 // scan blocks (256 thr, 32 b each)

#define NT1 1025                 // tier1 entries (z in [-128,128], dz=1/4)
#define NT2 1025                 // tier2 entries (z in [-8192,8192], dz=16)
#define NEE 1024                 // encoder pairs (x in [-8,8], dx=1/64)
#define NENT (NT1 + NT2 + NEE)

#define ENT_F 10                       // 40B entry stride
#define ZT_FLOATS (ENT_F * (NT1 + NT2))   // 20500 floats = 82KB
#define T2_BASEF (ENT_F * NT1)         // 10250
#define ET2G_OFF ZT_FLOATS
#define TABG_FLOATS (ZT_FLOATS + 2048) // 22548

#define NXI 1024
#define XSF 64.0f
#define XOF 512.0f

#if __has_builtin(__builtin_amdgcn_rcpf)
#define RCPF(x) __builtin_amdgcn_rcpf(x)
#else
#define RCPF(x) (1.0f / (x))
#endif
#if __has_builtin(__builtin_amdgcn_sqrtf)
#define SQRTF(x) __builtin_amdgcn_sqrtf(x)
#else
#define SQRTF(x) sqrtf(x)
#endif

__device__ __forceinline__ float sp_precise(float a) {
  return fmaxf(a, 0.0f) + log1pf(expf(-fabsf(a)));
}
__device__ __forceinline__ float wsum64(float v) {
  #pragma unroll
  for (int m = 1; m <= 32; m <<= 1) v += __shfl_xor(v, m);
  return v;
}
// xor4 within 32-lane halves (BitMode: (xor<<10)|0x1F)
__device__ __forceinline__ float swz4(float v) {
  return __int_as_float(__builtin_amdgcn_ds_swizzle(__float_as_int(v), 0x101F));
}
template <int CTRL>
__device__ __forceinline__ float dpp_mov(float v) {
  return __int_as_float(
      __builtin_amdgcn_update_dpp(0, __float_as_int(v), CTRL, 0xF, 0xF, true));
}
// quad_perm [1,0,3,2] = 0xB1 (xor1), [2,3,0,1] = 0x4E (xor2) -- R3-verified

// ---------------- build: one wave per entry ----------------
__global__ __launch_bounds__(256) void build_tabs(
    const float* __restrict__ ew1, const float* __restrict__ eb1,
    const float* __restrict__ ew2, const float* __restrict__ eb2,
    const float* __restrict__ fw1, const float* __restrict__ fb1,
    const float* __restrict__ fw2, const float* __restrict__ fb2,
    const float* __restrict__ hw1, const float* __restrict__ hb1,
    const float* __restrict__ hw2, const float* __restrict__ hb2,
    const float* __restrict__ gw1, const float* __restrict__ gb1,
    const float* __restrict__ gw2, const float* __restrict__ gb2,
    const float* __restrict__ pw1, const float* __restrict__ pb1,
    const float* __restrict__ pw2, const float* __restrict__ pb2,
    float* __restrict__ tabs, int* __restrict__ ctr)
{
  const int gtid = blockIdx.x * 256 + threadIdx.x;
  if (gtid == 0) *ctr = 0;
  const int ent  = gtid >> 6;
  const int lane = threadIdx.x & 63;
  if (ent >= NENT) return;

  if (ent < NT1 + NT2) {
    const bool t1 = ent < NT1;
    const int  i  = t1 ? ent : (ent - NT1);
    const float z = t1 ? (-128.0f + (float)i * 0.25f)
                       : (-8192.0f + (float)i * 16.0f);
    const int basef = (t1 ? 0 : T2_BASEF) + ENT_F * i;

    const float az = fmaf(z, fw1[lane], fb1[lane]);
    const float wc = fw1[64 + lane], w2 = fw2[lane];
    float s0 = sp_precise(fmaf(-3.0f, wc, az)) * w2;
    float s1 = sp_precise(fmaf(-1.0f, wc, az)) * w2;
    float s2 = sp_precise(fmaf( 1.0f, wc, az)) * w2;
    float s3 = sp_precise(fmaf( 3.0f, wc, az)) * w2;
    float sh = sp_precise(fmaf(z, hw1[lane], hb1[lane])) * hw2[lane];
    float sg = sp_precise(fmaf(z, gw1[lane], gb1[lane])) * gw2[lane];
    float sp = sp_precise(fmaf(z, pw1[lane], pb1[lane])) * pw2[lane];
    s0 = wsum64(s0); s1 = wsum64(s1); s2 = wsum64(s2); s3 = wsum64(s3);
    sh = wsum64(sh); sg = wsum64(sg); sp = wsum64(sp);
    if (lane == 0) {
      const float fb = fb2[0];
      tabs[basef + 0] = s0 + fb;
      tabs[basef + 1] = s1 + fb;
      tabs[basef + 2] = s2 + fb;
      tabs[basef + 3] = s3 + fb;
      tabs[basef + 4] = sh + hb2[0];
      tabs[basef + 5] = 1.0f / (1.0f + expf(-(sg + gb2[0])));
      tabs[basef + 6] = sp + pb2[0];
      tabs[basef + 7] = 0.0f;
      tabs[basef + 8] = 0.0f;
      tabs[basef + 9] = 0.0f;
    }
  } else {
    const int i = ent - (NT1 + NT2);
    const float x0 = -8.0f + (float)i * (1.0f / 64.0f);
    const float x1 = x0 + (1.0f / 64.0f);
    const float w = ew1[lane], bb = eb1[lane], w2 = ew2[lane];
    float s0 = sp_precise(fmaf(x0, w, bb)) * w2;
    float s1 = sp_precise(fmaf(x1, w, bb)) * w2;
    s0 = wsum64(s0); s1 = wsum64(s1);
    if (lane == 0) {
      const float eb = eb2[0];
      ((float2*)(tabs + ET2G_OFF))[i] = make_float2(s0 + eb, s1 + eb);
    }
  }
}

// ---------------- pre-pass: ctx[t,b] = enc(xs[t,b]) ----------------
__global__ __launch_bounds__(256) void ctx_pre(
    const float* __restrict__ xs, const float* __restrict__ tabs,
    float* __restrict__ ctx)
{
  const int i = blockIdx.x * 256 + threadIdx.x;
  const float2* et2 = (const float2*)(tabs + ET2G_OFF);
  const float s = fmaf(xs[i], XSF, XOF);
  const float sc = fminf(fmaxf(s, 0.0f), (float)(NXI - 1));
  const int ii = (int)sc;
  const float fr = s - (float)ii;
  const float2 e = et2[ii];
  ctx[i] = fmaf(fr, e.y - e.x, e.x);
}

// ---------------- scan: 8-lane groups, 8 b/wave ----------------
__global__ __launch_bounds__(256) void sde_scan(
    const float* __restrict__ xs, const float* __restrict__ ts,
    const float* __restrict__ noise_std, const float* __restrict__ eps0,
    const float* __restrict__ dW, const float* __restrict__ ctx,
    const float* __restrict__ qw,  const float* __restrict__ qb,
    const float* __restrict__ fw1, const float* __restrict__ fb1,
    const float* __restrict__ fw2, const float* __restrict__ fb2,
    const float* __restrict__ hw1, const float* __restrict__ hb1,
    const float* __restrict__ hw2, const float* __restrict__ hb2,
    const float* __restrict__ gw1, const float* __restrict__ gb1,
    const float* __restrict__ gw2, const float* __restrict__ gb2,
    const float* __restrict__ pw1, const float* __restrict__ pb1,
    const float* __restrict__ pw2, const float* __restrict__ pb2,
    const float* __restrict__ pz0_mean, const float* __restrict__ pz0_logstd,
    const float* __restrict__ tabsrc,
    int* __restrict__ ctr, float* __restrict__ partA, float* __restrict__ partB,
    float* __restrict__ out)
{
  __shared__ __align__(16) float tab[ZT_FLOATS];
  __shared__ float la[256], lb[256];
  __shared__ int lastflag;

  const int tid = threadIdx.x;
  const int li  = tid & 7;               // lane within 8-lane group
  const int b   = blockIdx.x * 32 + (tid >> 3);

  { // stage z-table (5125 float4)
    const float4* s4 = (const float4*)tabsrc;
    float4* d4 = (float4*)tab;
    for (int i = tid; i < ZT_FLOATS / 4; i += 256) d4[i] = s4[i];
  }
  __syncthreads();

  const float fb2s = fb2[0], hb2s = hb2[0], gb2s = gb2[0], pb2s = pb2[0];
  const float qw0 = qw[0], qw1 = qw[1], qb0 = qb[0], qb1 = qb[1];
  const float ns = noise_std[0];
  const float inv_ns = 1.0f / ns;
  const float nh_i2 = -0.5f * inv_ns * inv_ns;
  const float pm = pz0_mean[0], pls = pz0_logstd[0];

  auto hgp_exact = [&](float z_, float& hv_, float& gv_, float& pv_) {
    float sh = 0.f, sg = 0.f, sp = 0.f;
    for (int j = 0; j < 64; ++j) {
      sh = fmaf(sp_precise(fmaf(z_, hw1[j], hb1[j])), hw2[j], sh);
      sg = fmaf(sp_precise(fmaf(z_, gw1[j], gb1[j])), gw2[j], sg);
      sp = fmaf(sp_precise(fmaf(z_, pw1[j], pb1[j])), pw2[j], sp);
    }
    hv_ = sh + hb2s;
    gv_ = 1.0f / (1.0f + expf(-(sg + gb2s)));
    pv_ = sp + pb2s;
  };
  auto f_exact = [&](float z_, float c_) {
    float s = 0.f;
    for (int j = 0; j < 64; ++j)
      s = fmaf(sp_precise(fmaf(z_, fw1[j], fmaf(c_, fw1[64 + j], fb1[j]))), fw2[j], s);
    return s + fb2s;
  };
  // two-tier index -> float base of entry fi (reads fi, fi+1 at +0 / +ENT_F)
  auto zidx = [&](float z_, int& basef_, float& frac_, bool& inr_) {
    const float s1 = fmaf(z_, 4.0f, 512.0f);        // tier1 (dz=1/4)
    const float s2v = fmaf(z_, 0.0625f, 512.0f);    // tier2 (dz=16)
    const bool t1 = (s1 >= 0.0f) && (s1 <= 1024.0f);
    const bool t2 = (s2v >= 0.0f) && (s2v <= 1024.0f);
    inr_ = t1 || t2;
    const float sf = t1 ? s1 : fminf(fmaxf(s2v, 0.0f), 1024.0f);
    const int fi = min((int)sf, 1023);
    basef_ = (t1 ? 0 : T2_BASEF) + ENT_F * fi;
    frac_ = sf - (float)fi;
  };

  // ---- prologue (all 8 lanes redundant per b) ----
  const float c0v = ctx[b];
  const float qm  = fmaf(c0v, qw0, qb0);
  const float qls = fmaf(c0v, qw1, qb1);
  float z = fmaf(__expf(qls), eps0[b], qm);
  const float dqm = qm - pm;
  const float kl = (pls - qls)
                 + (__expf(2.0f * qls) + dqm * dqm) * (0.5f * __expf(-2.0f * pls))
                 - 0.5f;

  // 4-deep prefetch: slot j holds {xs[k B+b], ctx[k B+b], dW[k B+b]} for k=j
  float xbuf0 = xs[0 * B_SZ + b], cbuf0 = ctx[0 * B_SZ + b], wbuf0 = dW[0 * B_SZ + b];
  float xbuf1 = xs[1 * B_SZ + b], cbuf1 = ctx[1 * B_SZ + b], wbuf1 = dW[1 * B_SZ + b];
  float xbuf2 = xs[2 * B_SZ + b], cbuf2 = ctx[2 * B_SZ + b], wbuf2 = dW[2 * B_SZ + b];
  float xbuf3 = xs[3 * B_SZ + b], cbuf3 = ctx[3 * B_SZ + b], wbuf3 = dW[3 * B_SZ + b];

  bool zin; int zb; float zfr;
  zidx(z, zb, zfr, zin);

  float lrs = 0.0f, lps = 0.0f;
  const int part = li & 3;
  const int loff = ((li >> 2) * ENT_F) + 2 * part;   // lane's float2 slice

  // one step: read at z_k -> fv,hv,gv (z_k) for lr & z-update; pv(z_k) for lp_k
#define STEP(K, J) { \
    const int kc = min((K) + 1, T_SZ - 1); \
    const float dt = ts[kc] - ts[(K)]; \
    const float sq = SQRTF(dt); \
    const float cc = cbuf##J; \
    const float c2 = cc * cc; \
    const float p1c = c2 - 1.0f, p3c = c2 - 9.0f; \
    const float L0 = p1c * (cc - 3.0f) * (-1.0f / 48.0f); \
    const float L1 = p3c * (cc - 1.0f) * ( 1.0f / 16.0f); \
    const float L2 = p3c * (cc + 1.0f) * (-1.0f / 16.0f); \
    const float L3 = p1c * (cc + 3.0f) * ( 1.0f / 48.0f); \
    const bool cin = fabsf(cc) <= 3.0f; \
    const float2 va = *(const float2*)(tab + zb + loff); \
    const float wz = (li < 4) ? (1.0f - zfr) : zfr; \
    const float Asel = (part == 0) ? L0 : ((part == 1) ? L2 : 1.0f); \
    const float Bsel = (part == 0) ? L1 : ((part == 1) ? L3 : 0.0f); \
    const float r0 = wz * fmaf(Asel, va.x, Bsel * va.y); \
    const float r1 = wz * va.y; \
    const float u0 = r0 + swz4(r0); \
    const float u1 = r1 + swz4(r1); \
    const float fv01 = u0 + dpp_mov<0xB1>(u0); \
    const float X = (part < 2) ? fv01 : u0; \
    const float xX = dpp_mov<0x4E>(X); \
    const float xY = dpp_mov<0x4E>(u1); \
    float FV = (part < 2) ? fv01 : xX; \
    float HV = (part == 0) ? xX : u0; \
    float GV = (part == 0) ? xY : u1; \
    float PV = (part == 1) ? xX : u0; \
    if (!(zin && cin)) FV = f_exact(z, cc); \
    if (!zin) { float he, ge, pe; hgp_exact(z, he, ge, pe); HV = he; GV = ge; PV = pe; } \
    const float gvs = fmaxf(GV, 1e-6f); \
    const float uu = (FV - HV) * RCPF(gvs); \
    lrs = fmaf((0.5f * dt) * uu, uu, lrs); \
    const float zn = fmaf(gvs * wbuf##J, sq, fmaf(FV, dt, z)); \
    const float znb = dpp_mov<0xB1>(zn); \
    z = (li & 1) ? znb : zn; \
    const float d_ = xbuf##J - PV; \
    lps = fmaf(nh_i2 * d_, d_, lps); \
    /* refill slot J for step K+4 */ \
    const int kk_ = (K) + 4; \
    const int ixc_ = min(kk_, T_SZ - 1) * B_SZ + b; \
    const float xb_n = xs[ixc_]; \
    const float cb_n = ctx[ixc_]; \
    const float wb_n = (kk_ < T_SZ - 1) ? dW[kk_ * B_SZ + b] : 0.0f; \
    zidx(z, zb, zfr, zin); \
    xbuf##J = xb_n; cbuf##J = cb_n; wbuf##J = wb_n; \
  }

  // ---- 128 iterations (k=0..127; k=127 has dt=0, dW=0 -> lp only) ----
  for (int k = 0; k < T_SZ; k += 4) {
    STEP(k, 0); STEP(k + 1, 1); STEP(k + 2, 2); STEP(k + 3, 3);
  }
#undef STEP

  // ---- fused deterministic reduction ----
  la[tid] = (li == 1) ? lps : 0.0f;          // lp valid on odd lanes
  lb[tid] = (li == 0) ? (kl + lrs) : 0.0f;   // lr valid on even lanes
  __syncthreads();
  for (int s = 128; s > 0; s >>= 1) {
    if (tid < s) { la[tid] += la[tid + s]; lb[tid] += lb[tid + s]; }
    __syncthreads();
  }
  if (tid == 0) {
    partA[blockIdx.x] = la[0]; partB[blockIdx.x] = lb[0];
    __threadfence();
    lastflag = (atomicAdd(ctr, 1) == NBLK - 1) ? 1 : 0;
  }
  __syncthreads();
  if (lastflag) {
    __threadfence();
    la[tid] = partA[tid]; lb[tid] = partB[tid];
    __syncthreads();
    for (int s = 128; s > 0; s >>= 1) {
      if (tid < s) { la[tid] += la[tid + s]; lb[tid] += lb[tid + s]; }
      __syncthreads();
    }
    if (tid == 0) {
      out[0] = la[0] / (float)B_SZ
             + (float)T_SZ * (-__logf(ns) - 0.9189385332046727f);
      out[1] = lb[0] / (float)B_SZ;
    }
  }
}

extern "C" void kernel_launch(void* const* d_in, const int* in_sizes, int n_in,
                              void* d_out, int out_size, void* d_ws, size_t ws_size,
                              hipStream_t stream) {
  const float* xs        = (const float*)d_in[0];
  const float* ts        = (const float*)d_in[1];
  const float* noise_std = (const float*)d_in[2];
  const float* eps0      = (const float*)d_in[3];
  const float* dW        = (const float*)d_in[4];
  const float* ew1 = (const float*)d_in[5];
  const float* eb1 = (const float*)d_in[6];
  const float* ew2 = (const float*)d_in[7];
  const float* eb2 = (const float*)d_in[8];
  const float* qw  = (const float*)d_in[9];
  const float* qb  = (const float*)d_in[10];
  const float* fw1 = (const float*)d_in[11];
  const float* fb1 = (const float*)d_in[12];
  const float* fw2 = (const float*)d_in[13];
  const float* fb2 = (const float*)d_in[14];
  const float* hw1 = (const float*)d_in[15];
  const float* hb1 = (const float*)d_in[16];
  const float* hw2 = (const float*)d_in[17];
  const float* hb2 = (const float*)d_in[18];
  const float* gw1 = (const float*)d_in[19];
  const float* gb1 = (const float*)d_in[20];
  const float* gw2 = (const float*)d_in[21];
  const float* gb2 = (const float*)d_in[22];
  const float* pw1 = (const float*)d_in[23];
  const float* pb1 = (const float*)d_in[24];
  const float* pw2 = (const float*)d_in[25];
  const float* pb2 = (const float*)d_in[26];
  const float* pz0_mean   = (const float*)d_in[27];
  const float* pz0_logstd = (const float*)d_in[28];
  float* out = (float*)d_out;

  float* tabs  = (float*)d_ws;                       // [TABG_FLOATS]
  int*   ctr   = (int*)(tabs + TABG_FLOATS);         // [1] (+pad)
  float* partA = tabs + TABG_FLOATS + 4;             // [NBLK]
  float* partB = partA + NBLK;                       // [NBLK]
  float* ctxb  = partB + NBLK;                       // [T*B]

  build_tabs<<<(NENT * 64 + 255) / 256, 256, 0, stream>>>(
      ew1, eb1, ew2, eb2, fw1, fb1, fw2, fb2,
      hw1, hb1, hw2, hb2, gw1, gb1, gw2, gb2,
      pw1, pb1, pw2, pb2, tabs, ctr);

  ctx_pre<<<(T_SZ * B_SZ) / 256, 256, 0, stream>>>(xs, tabs, ctxb);

  sde_scan<<<NBLK, 256, 0, stream>>>(
      xs, ts, noise_std, eps0, dW, ctxb, qw, qb,
      fw1, fb1, fw2, fb2, hw1, hb1, hw2, hb2,
      gw1, gb1, gw2, gb2, pw1, pb1, pw2, pb2,
      pz0_mean, pz0_logstd, tabs, ctr, partA, partB, out);
}

// Round 17
// 60.129 us; speedup vs baseline: 1.1621x; 1.1053x over previous
//
#include <hip/hip_runtime.h>
#include <math.h>

// LatentSDE (L=C=D=1, H=64), all nets tabulated. R12-R16 established:
// wall = 127 x per-step serial chain latency (independent of wave/CU count);
// R16's chain had TWO LDS-pipe ops (divergent ds_read_b64 + ds_swizzle).
// R17: ONE ds_read_b128 per group-step + DPP-only cross-lane (VALU pipe).
// 4-lane groups, entry = 8 floats {f-3,f-1,f1,f3,h,g,p,pad}; lane p reads
// float4 at base+16p (entries zi,zi+1 = 64B contiguous, conflict-free
// within group). xor2-add -> fv(even)/hgp(odd); xor1 -> g,h to even;
// zn on lane0; quad-broadcast 0x00. Numerics unchanged (absmax 0.0
// R10-R16): tier1 z[-128,128] dz=1/4, tier2 z[-8192,8192] dz=16,
// cubic-Lagrange c-nodes {-3,-1,1,3}, exact-MLP fallback (group-uniform).

#define B_SZ 8192
#define T_SZ 128
#define NBLK 128                 // scan blocks (256 thr, 64 b each)

#define NT1 1025                 // tier1 entries (z in [-128,128], dz=1/4)
#define NT2 1025                 // tier2 entries (z in [-8192,8192], dz=16)
#define NEE 1024                 // encoder pairs (x in [-8,8], dx=1/64)
#define NENT (NT1 + NT2 + NEE)

#define ENT_F 8                        // 32B entry stride
#define ZT_FLOATS (ENT_F * (NT1 + NT2))   // 16400 floats = 65.6KB
#define T2_BASEF (ENT_F * NT1)         // 8200
#define ET2G_OFF ZT_FLOATS
#define TABG_FLOATS (ZT_FLOATS + 2048) // 18448

#define NXI 1024
#define XSF 64.0f
#define XOF 512.0f

#if __has_builtin(__builtin_amdgcn_rcpf)
#define RCPF(x) __builtin_amdgcn_rcpf(x)
#else
#define RCPF(x) (1.0f / (x))
#endif
#if __has_builtin(__builtin_amdgcn_sqrtf)
#define SQRTF(x) __builtin_amdgcn_sqrtf(x)
#else
#define SQRTF(x) sqrtf(x)
#endif

__device__ __forceinline__ float sp_precise(float a) {
  return fmaxf(a, 0.0f) + log1pf(expf(-fabsf(a)));
}
__device__ __forceinline__ float wsum64(float v) {
  #pragma unroll
  for (int m = 1; m <= 32; m <<= 1) v += __shfl_xor(v, m);
  return v;
}
template <int CTRL>
__device__ __forceinline__ float dpp_mov(float v) {
  return __int_as_float(
      __builtin_amdgcn_update_dpp(0, __float_as_int(v), CTRL, 0xF, 0xF, true));
}
// quad_perm ctrls: 0xB1 = [1,0,3,2] (xor1), 0x4E = [2,3,0,1] (xor2),
// 0x00 = [0,0,0,0] (broadcast lane0 of quad). R3/R16-verified encodings.

// ---------------- build: one wave per entry ----------------
__global__ __launch_bounds__(256) void build_tabs(
    const float* __restrict__ ew1, const float* __restrict__ eb1,
    const float* __restrict__ ew2, const float* __restrict__ eb2,
    const float* __restrict__ fw1, const float* __restrict__ fb1,
    const float* __restrict__ fw2, const float* __restrict__ fb2,
    const float* __restrict__ hw1, const float* __restrict__ hb1,
    const float* __restrict__ hw2, const float* __restrict__ hb2,
    const float* __restrict__ gw1, const float* __restrict__ gb1,
    const float* __restrict__ gw2, const float* __restrict__ gb2,
    const float* __restrict__ pw1, const float* __restrict__ pb1,
    const float* __restrict__ pw2, const float* __restrict__ pb2,
    float* __restrict__ tabs, int* __restrict__ ctr)
{
  const int gtid = blockIdx.x * 256 + threadIdx.x;
  if (gtid == 0) *ctr = 0;
  const int ent  = gtid >> 6;
  const int lane = threadIdx.x & 63;
  if (ent >= NENT) return;

  if (ent < NT1 + NT2) {
    const bool t1 = ent < NT1;
    const int  i  = t1 ? ent : (ent - NT1);
    const float z = t1 ? (-128.0f + (float)i * 0.25f)
                       : (-8192.0f + (float)i * 16.0f);
    const int basef = (t1 ? 0 : T2_BASEF) + ENT_F * i;

    const float az = fmaf(z, fw1[lane], fb1[lane]);
    const float wc = fw1[64 + lane], w2 = fw2[lane];
    float s0 = sp_precise(fmaf(-3.0f, wc, az)) * w2;
    float s1 = sp_precise(fmaf(-1.0f, wc, az)) * w2;
    float s2 = sp_precise(fmaf( 1.0f, wc, az)) * w2;
    float s3 = sp_precise(fmaf( 3.0f, wc, az)) * w2;
    float sh = sp_precise(fmaf(z, hw1[lane], hb1[lane])) * hw2[lane];
    float sg = sp_precise(fmaf(z, gw1[lane], gb1[lane])) * gw2[lane];
    float sp = sp_precise(fmaf(z, pw1[lane], pb1[lane])) * pw2[lane];
    s0 = wsum64(s0); s1 = wsum64(s1); s2 = wsum64(s2); s3 = wsum64(s3);
    sh = wsum64(sh); sg = wsum64(sg); sp = wsum64(sp);
    if (lane == 0) {
      const float fb = fb2[0];
      tabs[basef + 0] = s0 + fb;
      tabs[basef + 1] = s1 + fb;
      tabs[basef + 2] = s2 + fb;
      tabs[basef + 3] = s3 + fb;
      tabs[basef + 4] = sh + hb2[0];
      tabs[basef + 5] = 1.0f / (1.0f + expf(-(sg + gb2[0])));
      tabs[basef + 6] = sp + pb2[0];
      tabs[basef + 7] = 0.0f;
    }
  } else {
    const int i = ent - (NT1 + NT2);
    const float x0 = -8.0f + (float)i * (1.0f / 64.0f);
    const float x1 = x0 + (1.0f / 64.0f);
    const float w = ew1[lane], bb = eb1[lane], w2 = ew2[lane];
    float s0 = sp_precise(fmaf(x0, w, bb)) * w2;
    float s1 = sp_precise(fmaf(x1, w, bb)) * w2;
    s0 = wsum64(s0); s1 = wsum64(s1);
    if (lane == 0) {
      const float eb = eb2[0];
      ((float2*)(tabs + ET2G_OFF))[i] = make_float2(s0 + eb, s1 + eb);
    }
  }
}

// ---------------- pre-pass: ctx[t,b] = enc(xs[t,b]) ----------------
__global__ __launch_bounds__(256) void ctx_pre(
    const float* __restrict__ xs, const float* __restrict__ tabs,
    float* __restrict__ ctx)
{
  const int i = blockIdx.x * 256 + threadIdx.x;
  const float2* et2 = (const float2*)(tabs + ET2G_OFF);
  const float s = fmaf(xs[i], XSF, XOF);
  const float sc = fminf(fmaxf(s, 0.0f), (float)(NXI - 1));
  const int ii = (int)sc;
  const float fr = s - (float)ii;
  const float2 e = et2[ii];
  ctx[i] = fmaf(fr, e.y - e.x, e.x);
}

// ---------------- scan: 4-lane groups, 16 b/wave ----------------
__global__ __launch_bounds__(256) void sde_scan(
    const float* __restrict__ xs, const float* __restrict__ ts,
    const float* __restrict__ noise_std, const float* __restrict__ eps0,
    const float* __restrict__ dW, const float* __restrict__ ctx,
    const float* __restrict__ qw,  const float* __restrict__ qb,
    const float* __restrict__ fw1, const float* __restrict__ fb1,
    const float* __restrict__ fw2, const float* __restrict__ fb2,
    const float* __restrict__ hw1, const float* __restrict__ hb1,
    const float* __restrict__ hw2, const float* __restrict__ hb2,
    const float* __restrict__ gw1, const float* __restrict__ gb1,
    const float* __restrict__ gw2, const float* __restrict__ gb2,
    const float* __restrict__ pw1, const float* __restrict__ pb1,
    const float* __restrict__ pw2, const float* __restrict__ pb2,
    const float* __restrict__ pz0_mean, const float* __restrict__ pz0_logstd,
    const float* __restrict__ tabsrc,
    int* __restrict__ ctr, float* __restrict__ partA, float* __restrict__ partB,
    float* __restrict__ out)
{
  __shared__ __align__(16) float tab[ZT_FLOATS];
  __shared__ float la[256], lb[256];
  __shared__ int lastflag;

  const int tid  = threadIdx.x;
  const int part = tid & 3;                 // lane within 4-lane group
  const int b    = blockIdx.x * 64 + (tid >> 2);

  { // stage z-table (4100 float4)
    const float4* s4 = (const float4*)tabsrc;
    float4* d4 = (float4*)tab;
    for (int i = tid; i < ZT_FLOATS / 4; i += 256) d4[i] = s4[i];
  }
  __syncthreads();

  const float fb2s = fb2[0], hb2s = hb2[0], gb2s = gb2[0], pb2s = pb2[0];
  const float qw0 = qw[0], qw1 = qw[1], qb0 = qb[0], qb1 = qb[1];
  const float ns = noise_std[0];
  const float inv_ns = 1.0f / ns;
  const float nh_i2 = -0.5f * inv_ns * inv_ns;
  const float pm = pz0_mean[0], pls = pz0_logstd[0];

  auto hgp_exact = [&](float z_, float& hv_, float& gv_, float& pv_) {
    float sh = 0.f, sg = 0.f, sp = 0.f;
    for (int j = 0; j < 64; ++j) {
      sh = fmaf(sp_precise(fmaf(z_, hw1[j], hb1[j])), hw2[j], sh);
      sg = fmaf(sp_precise(fmaf(z_, gw1[j], gb1[j])), gw2[j], sg);
      sp = fmaf(sp_precise(fmaf(z_, pw1[j], pb1[j])), pw2[j], sp);
    }
    hv_ = sh + hb2s;
    gv_ = 1.0f / (1.0f + expf(-(sg + gb2s)));
    pv_ = sp + pb2s;
  };
  auto f_exact = [&](float z_, float c_) {
    float s = 0.f;
    for (int j = 0; j < 64; ++j)
      s = fmaf(sp_precise(fmaf(z_, fw1[j], fmaf(c_, fw1[64 + j], fb1[j]))), fw2[j], s);
    return s + fb2s;
  };
  // two-tier index -> float base of entry fi; reads fi (offs 0..7) and
  // fi+1 (offs 8..15); lane reads float4 at base + 4*part.
  auto zidx = [&](float z_, int& basef_, float& frac_, bool& inr_) {
    const float s1 = fmaf(z_, 4.0f, 512.0f);        // tier1 (dz=1/4)
    const float s2v = fmaf(z_, 0.0625f, 512.0f);    // tier2 (dz=16)
    const bool t1 = (s1 >= 0.0f) && (s1 <= 1024.0f);
    const bool t2 = (s2v >= 0.0f) && (s2v <= 1024.0f);
    inr_ = t1 || t2;
    const float sf = t1 ? s1 : fminf(fmaxf(s2v, 0.0f), 1024.0f);
    const int fi = min((int)sf, 1023);
    basef_ = (t1 ? 0 : T2_BASEF) + ENT_F * fi;
    frac_ = sf - (float)fi;
  };

  // ---- prologue (4 lanes redundant per b) ----
  const float c0v = ctx[b];
  const float qm  = fmaf(c0v, qw0, qb0);
  const float qls = fmaf(c0v, qw1, qb1);
  float z = fmaf(__expf(qls), eps0[b], qm);
  const float dqm = qm - pm;
  const float kl = (pls - qls)
                 + (__expf(2.0f * qls) + dqm * dqm) * (0.5f * __expf(-2.0f * pls))
                 - 0.5f;

  // 4-deep prefetch: slot j holds {xs,ctx,dW}[k=j]
  float xbuf0 = xs[0 * B_SZ + b], cbuf0 = ctx[0 * B_SZ + b], wbuf0 = dW[0 * B_SZ + b];
  float xbuf1 = xs[1 * B_SZ + b], cbuf1 = ctx[1 * B_SZ + b], wbuf1 = dW[1 * B_SZ + b];
  float xbuf2 = xs[2 * B_SZ + b], cbuf2 = ctx[2 * B_SZ + b], wbuf2 = dW[2 * B_SZ + b];
  float xbuf3 = xs[3 * B_SZ + b], cbuf3 = ctx[3 * B_SZ + b], wbuf3 = dW[3 * B_SZ + b];

  bool zin; int zb; float zfr;
  zidx(z, zb, zfr, zin);

  float lrs = 0.0f, lps = 0.0f;
  const int loff = 4 * part;     // lane's float4 within the 64B entry-pair

  // step k: table values at z_k -> fv,hv,gv (lr, z-update), pv (lp_k)
#define STEP(K, J) { \
    const int kc = min((K) + 1, T_SZ - 1); \
    const float dt = ts[kc] - ts[(K)]; \
    const float sq = SQRTF(dt); \
    const float cc = cbuf##J; \
    const float c2 = cc * cc; \
    const float p1c = c2 - 1.0f, p3c = c2 - 9.0f; \
    const float L0 = p1c * (cc - 3.0f) * (-1.0f / 48.0f); \
    const float L1 = p3c * (cc - 1.0f) * ( 1.0f / 16.0f); \
    const float L2 = p3c * (cc + 1.0f) * (-1.0f / 16.0f); \
    const float L3 = p1c * (cc + 3.0f) * ( 1.0f / 48.0f); \
    const bool cin = fabsf(cc) <= 3.0f; \
    const float4 va = *(const float4*)(tab + zb + loff); \
    const float wz = (part < 2) ? (1.0f - zfr) : zfr; \
    const float dotL = fmaf(L3, va.w, fmaf(L2, va.z, fmaf(L1, va.y, L0 * va.x))); \
    float sF = wz * dotL;          /* even parts: f contribution */ \
    float sG = wz * va.y;          /* odd parts: g */ \
    float sH = wz * va.x;          /* odd parts: h */ \
    float sP = wz * va.z;          /* odd parts: p */ \
    sF += dpp_mov<0x4E>(sF);       /* p0+p2, p1+p3 */ \
    sG += dpp_mov<0x4E>(sG); \
    sH += dpp_mov<0x4E>(sH); \
    sP += dpp_mov<0x4E>(sP); \
    float FV = sF;                 /* valid on p0,p2 */ \
    float GV = dpp_mov<0xB1>(sG);  /* odd->even */ \
    float HV = dpp_mov<0xB1>(sH); \
    float PV = sP;                 /* valid on p1,p3 */ \
    if (!(zin && cin)) FV = f_exact(z, cc); \
    if (!zin) { float he, ge, pe; hgp_exact(z, he, ge, pe); HV = he; GV = ge; PV = pe; } \
    const float gvs = fmaxf(GV, 1e-6f); \
    const float uu = (FV - HV) * RCPF(gvs); \
    lrs = fmaf((0.5f * dt) * uu, uu, lrs);        /* valid p0 */ \
    const float d_ = xbuf##J - PV; \
    lps = fmaf(nh_i2 * d_, d_, lps);              /* valid p1 */ \
    const float zn = fmaf(gvs * wbuf##J, sq, fmaf(FV, dt, z)); \
    z = dpp_mov<0x00>(zn);         /* broadcast quad-lane0 */ \
    /* refill slot J for step K+4 */ \
    const int kk_ = (K) + 4; \
    const int ixc_ = min(kk_, T_SZ - 1) * B_SZ + b; \
    const float xb_n = xs[ixc_]; \
    const float cb_n = ctx[ixc_]; \
    const float wb_n = (kk_ < T_SZ - 1) ? dW[kk_ * B_SZ + b] : 0.0f; \
    zidx(z, zb, zfr, zin); \
    xbuf##J = xb_n; cbuf##J = cb_n; wbuf##J = wb_n; \
  }

  // ---- 128 iterations (k=127: dt=0, dW=0 -> lp only) ----
  for (int k = 0; k < T_SZ; k += 4) {
    STEP(k, 0); STEP(k + 1, 1); STEP(k + 2, 2); STEP(k + 3, 3);
  }
#undef STEP

  // ---- fused deterministic reduction ----
  la[tid] = (part == 1) ? lps : 0.0f;
  lb[tid] = (part == 0) ? (kl + lrs) : 0.0f;
  __syncthreads();
  for (int s = 128; s > 0; s >>= 1) {
    if (tid < s) { la[tid] += la[tid + s]; lb[tid] += lb[tid + s]; }
    __syncthreads();
  }
  if (tid == 0) {
    partA[blockIdx.x] = la[0]; partB[blockIdx.x] = lb[0];
    __threadfence();
    lastflag = (atomicAdd(ctr, 1) == NBLK - 1) ? 1 : 0;
  }
  __syncthreads();
  if (lastflag) {
    __threadfence();
    la[tid] = (tid < NBLK) ? partA[tid] : 0.0f;
    lb[tid] = (tid < NBLK) ? partB[tid] : 0.0f;
    __syncthreads();
    for (int s = 128; s > 0; s >>= 1) {
      if (tid < s) { la[tid] += la[tid + s]; lb[tid] += lb[tid + s]; }
      __syncthreads();
    }
    if (tid == 0) {
      out[0] = la[0] / (float)B_SZ
             + (float)T_SZ * (-__logf(ns) - 0.9189385332046727f);
      out[1] = lb[0] / (float)B_SZ;
    }
  }
}

extern "C" void kernel_launch(void* const* d_in, const int* in_sizes, int n_in,
                              void* d_out, int out_size, void* d_ws, size_t ws_size,
                              hipStream_t stream) {
  const float* xs        = (const float*)d_in[0];
  const float* ts        = (const float*)d_in[1];
  const float* noise_std = (const float*)d_in[2];
  const float* eps0      = (const float*)d_in[3];
  const float* dW        = (const float*)d_in[4];
  const float* ew1 = (const float*)d_in[5];
  const float* eb1 = (const float*)d_in[6];
  const float* ew2 = (const float*)d_in[7];
  const float* eb2 = (const float*)d_in[8];
  const float* qw  = (const float*)d_in[9];
  const float* qb  = (const float*)d_in[10];
  const float* fw1 = (const float*)d_in[11];
  const float* fb1 = (const float*)d_in[12];
  const float* fw2 = (const float*)d_in[13];
  const float* fb2 = (const float*)d_in[14];
  const float* hw1 = (const float*)d_in[15];
  const float* hb1 = (const float*)d_in[16];
  const float* hw2 = (const float*)d_in[17];
  const float* hb2 = (const float*)d_in[18];
  const float* gw1 = (const float*)d_in[19];
  const float* gb1 = (const float*)d_in[20];
  const float* gw2 = (const float*)d_in[21];
  const float* gb2 = (const float*)d_in[22];
  const float* pw1 = (const float*)d_in[23];
  const float* pb1 = (const float*)d_in[24];
  const float* pw2 = (const float*)d_in[25];
  const float* pb2 = (const float*)d_in[26];
  const float* pz0_mean   = (const float*)d_in[27];
  const float* pz0_logstd = (const float*)d_in[28];
  float* out = (float*)d_out;

  float* tabs  = (float*)d_ws;                       // [TABG_FLOATS]
  int*   ctr   = (int*)(tabs + TABG_FLOATS);         // [1] (+pad)
  float* partA = tabs + TABG_FLOATS + 4;             // [NBLK]
  float* partB = partA + NBLK;                       // [NBLK]
  float* ctxb  = partB + NBLK;                       // [T*B]

  build_tabs<<<(NENT * 64 + 255) / 256, 256, 0, stream>>>(
      ew1, eb1, ew2, eb2, fw1, fb1, fw2, fb2,
      hw1, hb1, hw2, hb2, gw1, gb1, gw2, gb2,
      pw1, pb1, pw2, pb2, tabs, ctr);

  ctx_pre<<<(T_SZ * B_SZ) / 256, 256, 0, stream>>>(xs, tabs, ctxb);

  sde_scan<<<NBLK, 256, 0, stream>>>(
      xs, ts, noise_std, eps0, dW, ctxb, qw, qb,
      fw1, fb1, fw2, fb2, hw1, hb1, hw2, hb2,
      gw1, gb1, gw2, gb2, pw1, pb1, pw2, pb2,
      pz0_mean, pz0_logstd, tabs, ctr, partA, partB, out);
}